// Round 3
// baseline (1861.512 us; speedup 1.0000x reference)
//
#include <hip/hip_runtime.h>
#include <math.h>

#define BB 16
#define NN 577
#define CC 768
#define HH 12
#define HD 64
#define MM (BB*NN)      // 9232
#define LEFT 404
#define QT 16
#define NTILE 37        // ceil(577/16)

// ---------------------------------------------------------------------------
// QKV GEMM: qkv[i, col] = sum_k X[i,k] * W[col,k];  col -> (which, h, d)
// 128x128 tile, 256 threads, 8x8 micro   [validated round 1]
// ---------------------------------------------------------------------------
__global__ __launch_bounds__(256) void qkv_gemm(const float* __restrict__ X,
                                                const float* __restrict__ W,
                                                float* __restrict__ qb,
                                                float* __restrict__ kb,
                                                float* __restrict__ vb)
{
    __shared__ float Xs[16][128];
    __shared__ float Ws[16][128];
    const int t  = threadIdx.x;
    const int tx = t & 15, ty = t >> 4;
    const int m0 = blockIdx.x * 128;
    const int n0 = blockIdx.y * 128;
    const int sm = t & 127;
    const int sk = (t >> 7) * 8;

    float acc[8][8];
    #pragma unroll
    for (int i = 0; i < 8; ++i)
        #pragma unroll
        for (int j = 0; j < 8; ++j) acc[i][j] = 0.f;

    for (int kk = 0; kk < CC; kk += 16) {
        {
            const int gm = m0 + sm;
            float4 a0 = make_float4(0.f,0.f,0.f,0.f), a1 = a0;
            if (gm < MM) {
                const float* p = X + (size_t)gm * CC + kk + sk;
                a0 = *(const float4*)p;
                a1 = *(const float4*)(p + 4);
            }
            Xs[sk+0][sm] = a0.x; Xs[sk+1][sm] = a0.y; Xs[sk+2][sm] = a0.z; Xs[sk+3][sm] = a0.w;
            Xs[sk+4][sm] = a1.x; Xs[sk+5][sm] = a1.y; Xs[sk+6][sm] = a1.z; Xs[sk+7][sm] = a1.w;
            const float* pw = W + (size_t)(n0 + sm) * CC + kk + sk;
            float4 b0 = *(const float4*)pw;
            float4 b1 = *(const float4*)(pw + 4);
            Ws[sk+0][sm] = b0.x; Ws[sk+1][sm] = b0.y; Ws[sk+2][sm] = b0.z; Ws[sk+3][sm] = b0.w;
            Ws[sk+4][sm] = b1.x; Ws[sk+5][sm] = b1.y; Ws[sk+6][sm] = b1.z; Ws[sk+7][sm] = b1.w;
        }
        __syncthreads();
        #pragma unroll
        for (int k = 0; k < 16; ++k) {
            float a[8], bv[8];
            *(float4*)&a[0]  = *(const float4*)&Xs[k][ty*8];
            *(float4*)&a[4]  = *(const float4*)&Xs[k][ty*8+4];
            *(float4*)&bv[0] = *(const float4*)&Ws[k][tx*8];
            *(float4*)&bv[4] = *(const float4*)&Ws[k][tx*8+4];
            #pragma unroll
            for (int i = 0; i < 8; ++i)
                #pragma unroll
                for (int j = 0; j < 8; ++j)
                    acc[i][j] = fmaf(a[i], bv[j], acc[i][j]);
        }
        __syncthreads();
    }
    const int which = n0 / CC;          // uniform per block
    float* dst = (which == 0) ? qb : ((which == 1) ? kb : vb);
    #pragma unroll
    for (int i = 0; i < 8; ++i) {
        const int gm = m0 + ty*8 + i;
        if (gm >= MM) continue;
        const int b_ = gm / NN;
        const int n_ = gm - b_ * NN;
        #pragma unroll
        for (int j = 0; j < 8; ++j) {
            const int col = n0 + tx*8 + j - which * CC;   // 0..767
            const int h = col >> 6, d = col & 63;
            dst[(((size_t)b_ * HH + h) * NN + n_) * HD + d] = acc[i][j];
        }
    }
}

// ---------------------------------------------------------------------------
// proj GEMM: out[i,j] = sum_k A[i,k] * W[j,k] + bias[j]   [validated]
// ---------------------------------------------------------------------------
__global__ __launch_bounds__(256) void proj_gemm(const float* __restrict__ A,
                                                 const float* __restrict__ W,
                                                 const float* __restrict__ bias,
                                                 float* __restrict__ out)
{
    __shared__ float As[16][128];
    __shared__ float Ws[16][128];
    const int t  = threadIdx.x;
    const int tx = t & 15, ty = t >> 4;
    const int m0 = blockIdx.x * 128;
    const int n0 = blockIdx.y * 128;
    const int sm = t & 127;
    const int sk = (t >> 7) * 8;

    float acc[8][8];
    #pragma unroll
    for (int i = 0; i < 8; ++i)
        #pragma unroll
        for (int j = 0; j < 8; ++j) acc[i][j] = 0.f;

    for (int kk = 0; kk < CC; kk += 16) {
        {
            const int gm = m0 + sm;
            float4 a0 = make_float4(0.f,0.f,0.f,0.f), a1 = a0;
            if (gm < MM) {
                const float* p = A + (size_t)gm * CC + kk + sk;
                a0 = *(const float4*)p;
                a1 = *(const float4*)(p + 4);
            }
            As[sk+0][sm] = a0.x; As[sk+1][sm] = a0.y; As[sk+2][sm] = a0.z; As[sk+3][sm] = a0.w;
            As[sk+4][sm] = a1.x; As[sk+5][sm] = a1.y; As[sk+6][sm] = a1.z; As[sk+7][sm] = a1.w;
            const float* pw = W + (size_t)(n0 + sm) * CC + kk + sk;
            float4 b0 = *(const float4*)pw;
            float4 b1 = *(const float4*)(pw + 4);
            Ws[sk+0][sm] = b0.x; Ws[sk+1][sm] = b0.y; Ws[sk+2][sm] = b0.z; Ws[sk+3][sm] = b0.w;
            Ws[sk+4][sm] = b1.x; Ws[sk+5][sm] = b1.y; Ws[sk+6][sm] = b1.z; Ws[sk+7][sm] = b1.w;
        }
        __syncthreads();
        #pragma unroll
        for (int k = 0; k < 16; ++k) {
            float a[8], bv[8];
            *(float4*)&a[0]  = *(const float4*)&As[k][ty*8];
            *(float4*)&a[4]  = *(const float4*)&As[k][ty*8+4];
            *(float4*)&bv[0] = *(const float4*)&Ws[k][tx*8];
            *(float4*)&bv[4] = *(const float4*)&Ws[k][tx*8+4];
            #pragma unroll
            for (int i = 0; i < 8; ++i)
                #pragma unroll
                for (int j = 0; j < 8; ++j)
                    acc[i][j] = fmaf(a[i], bv[j], acc[i][j]);
        }
        __syncthreads();
    }
    #pragma unroll
    for (int i = 0; i < 8; ++i) {
        const int gm = m0 + ty*8 + i;
        if (gm >= MM) continue;
        #pragma unroll
        for (int j = 0; j < 8; ++j) {
            const int col = n0 + tx*8 + j;
            out[(size_t)gm * CC + col] = acc[i][j] + bias[col];
        }
    }
}

// ---------------------------------------------------------------------------
// Attention (fp32). PV loop bounded to valid V rows 0..576 (clean version).
// ---------------------------------------------------------------------------
__global__ __launch_bounds__(256) void attn_kernel(const float* __restrict__ qb,
                                                   const float* __restrict__ kb,
                                                   const float* __restrict__ vb,
                                                   float* __restrict__ ao)
{
    __shared__ float S[QT][580];
    __shared__ float Qs[QT][64];
    __shared__ float invZ[QT];
    const int bid  = blockIdx.x;
    const int tile = bid % NTILE;
    const int bh   = bid / NTILE;
    const int b    = bh / HH;
    const int h    = bh - b * HH;
    const int t    = threadIdx.x;
    const float* kbase = kb + (size_t)bh * NN * HD;
    const float* vbase = vb + (size_t)bh * NN * HD;

    {   // load Q tile
        const int r = t >> 4, d4 = (t & 15) * 4;
        const int nq = tile * QT + r;
        float4 qv = make_float4(0.f,0.f,0.f,0.f);
        if (nq < NN) qv = *(const float4*)(qb + ((size_t)bh * NN + nq) * HD + d4);
        *(float4*)&Qs[r][d4] = qv;
    }
    __syncthreads();

    {   // S = scale * Q K^T
        const int rg = t >> 6;
        const int lane = t & 63;
        float acc[4][10];
        #pragma unroll
        for (int r = 0; r < 4; ++r)
            #pragma unroll
            for (int c = 0; c < 10; ++c) acc[r][c] = 0.f;
        #pragma unroll
        for (int dc = 0; dc < 4; ++dc) {
            float qv[4][16];
            #pragma unroll
            for (int r = 0; r < 4; ++r) {
                *(float4*)&qv[r][0]  = *(const float4*)&Qs[rg*4+r][dc*16];
                *(float4*)&qv[r][4]  = *(const float4*)&Qs[rg*4+r][dc*16+4];
                *(float4*)&qv[r][8]  = *(const float4*)&Qs[rg*4+r][dc*16+8];
                *(float4*)&qv[r][12] = *(const float4*)&Qs[rg*4+r][dc*16+12];
            }
            #pragma unroll
            for (int c = 0; c < 10; ++c) {
                int n = lane + 64*c;
                if (n >= NN) n = NN - 1;
                const float* kp = kbase + (size_t)n * HD + dc*16;
                const float4 k0 = *(const float4*)kp;
                const float4 k1 = *(const float4*)(kp + 4);
                const float4 k2 = *(const float4*)(kp + 8);
                const float4 k3 = *(const float4*)(kp + 12);
                #pragma unroll
                for (int r = 0; r < 4; ++r) {
                    float s = acc[r][c];
                    s = fmaf(qv[r][0],  k0.x, s); s = fmaf(qv[r][1],  k0.y, s);
                    s = fmaf(qv[r][2],  k0.z, s); s = fmaf(qv[r][3],  k0.w, s);
                    s = fmaf(qv[r][4],  k1.x, s); s = fmaf(qv[r][5],  k1.y, s);
                    s = fmaf(qv[r][6],  k1.z, s); s = fmaf(qv[r][7],  k1.w, s);
                    s = fmaf(qv[r][8],  k2.x, s); s = fmaf(qv[r][9],  k2.y, s);
                    s = fmaf(qv[r][10], k2.z, s); s = fmaf(qv[r][11], k2.w, s);
                    s = fmaf(qv[r][12], k3.x, s); s = fmaf(qv[r][13], k3.y, s);
                    s = fmaf(qv[r][14], k3.z, s); s = fmaf(qv[r][15], k3.w, s);
                    acc[r][c] = s;
                }
            }
        }
        #pragma unroll
        for (int c = 0; c < 10; ++c) {
            const int n = lane + 64*c;
            if (n < NN) {
                #pragma unroll
                for (int r = 0; r < 4; ++r) S[rg*4+r][n] = acc[r][c] * 0.125f;
            }
        }
    }
    __syncthreads();

    {   // row softmax (store unnormalized e, invZ per row)
        const int w = t >> 6, lane = t & 63;
        #pragma unroll
        for (int rr = 0; rr < 4; ++rr) {
            const int r = w*4 + rr;
            float m = -1e30f;
            for (int n = lane; n < NN; n += 64) m = fmaxf(m, S[r][n]);
            #pragma unroll
            for (int off = 32; off; off >>= 1) m = fmaxf(m, __shfl_xor(m, off, 64));
            float s = 0.f;
            for (int n = lane; n < NN; n += 64) { float e = __expf(S[r][n] - m); S[r][n] = e; s += e; }
            #pragma unroll
            for (int off = 32; off; off >>= 1) s += __shfl_xor(s, off, 64);
            if (lane == 0) invZ[r] = 1.f / s;
        }
    }
    __syncthreads();

    {   // O = P V : rows 0..575 in float4 blocks, scalar tail row 576
        const int r = t >> 4, d4 = (t & 15) * 4;
        float ax = 0.f, ay = 0.f, az = 0.f, aw = 0.f;
        for (int n = 0; n < 576; n += 4) {
            const float4 p = *(const float4*)&S[r][n];
            const float* vp = vbase + (size_t)n * HD + d4;
            const float4 v0 = *(const float4*)vp;
            const float4 v1 = *(const float4*)(vp + HD);
            const float4 v2 = *(const float4*)(vp + 2*HD);
            const float4 v3 = *(const float4*)(vp + 3*HD);
            ax = fmaf(p.x, v0.x, ax); ay = fmaf(p.x, v0.y, ay); az = fmaf(p.x, v0.z, az); aw = fmaf(p.x, v0.w, aw);
            ax = fmaf(p.y, v1.x, ax); ay = fmaf(p.y, v1.y, ay); az = fmaf(p.y, v1.z, az); aw = fmaf(p.y, v1.w, aw);
            ax = fmaf(p.z, v2.x, ax); ay = fmaf(p.z, v2.y, ay); az = fmaf(p.z, v2.z, az); aw = fmaf(p.z, v2.w, aw);
            ax = fmaf(p.w, v3.x, ax); ay = fmaf(p.w, v3.y, ay); az = fmaf(p.w, v3.z, az); aw = fmaf(p.w, v3.w, aw);
        }
        {   // tail n = 576
            const float p576 = S[r][576];
            const float* vp = vbase + (size_t)576 * HD + d4;
            ax = fmaf(p576, vp[0], ax); ay = fmaf(p576, vp[1], ay);
            az = fmaf(p576, vp[2], az); aw = fmaf(p576, vp[3], aw);
        }
        const int nq = tile * QT + r;
        if (nq < NN) {
            const float iz = invZ[r];
            float4 o; o.x = ax*iz; o.y = ay*iz; o.z = az*iz; o.w = aw*iz;
            *(float4*)(ao + ((size_t)b * NN + nq) * CC + h*HD + d4) = o;
        }
    }
}

// ---------------------------------------------------------------------------
// CLS path v3 — natural fp32 port, reusing the validated fp32 q/k buffers
// (exactly how the reference derives cls_attn from the same attn tensor).
// Per (b,h): logits = q_cls . k_n * 0.125 (fp32, ascending d); max-subtracted
// softmax with expf; probabilities stored fp32.
// ---------------------------------------------------------------------------
__global__ __launch_bounds__(256) void cls_scores(const float* __restrict__ qb,
                                                  const float* __restrict__ kb,
                                                  float* __restrict__ P)
{
    const int bh = blockIdx.x;
    const int t = threadIdx.x;
    __shared__ float q[64];
    __shared__ float red[256];
    __shared__ float L[NN];
    if (t < 64) q[t] = qb[(size_t)bh * NN * HD + t];   // q row 0 (CLS)
    __syncthreads();
    float lmax = -1e30f;
    for (int n = t; n < NN; n += 256) {
        const float* kr = kb + ((size_t)bh * NN + n) * HD;
        float acc = 0.f;
        #pragma unroll
        for (int d = 0; d < 64; ++d) acc = fmaf(q[d], kr[d], acc);
        const float l = acc * 0.125f;
        L[n] = l;
        lmax = fmaxf(lmax, l);
    }
    red[t] = lmax; __syncthreads();
    for (int s = 128; s > 0; s >>= 1) { if (t < s) red[t] = fmaxf(red[t], red[t+s]); __syncthreads(); }
    const float m = red[0]; __syncthreads();
    float z = 0.f;
    for (int n = t; n < NN; n += 256) { const float e = expf(L[n] - m); L[n] = e; z += e; }
    red[t] = z; __syncthreads();
    for (int s = 128; s > 0; s >>= 1) { if (t < s) red[t] += red[t+s]; __syncthreads(); }
    const float Z = red[0];
    for (int n = t; n < NN; n += 256) P[(size_t)bh * NN + n] = L[n] / Z;
}

__global__ __launch_bounds__(256) void cls_mean32(const float* __restrict__ P,
                                                  float* __restrict__ cls32,
                                                  float* __restrict__ out_cls)
{
    const int b = blockIdx.x;
    for (int j = threadIdx.x; j < NN - 1; j += 256) {
        float s = 0.f;
        #pragma unroll
        for (int h = 0; h < HH; ++h) s += P[((size_t)(b * HH + h)) * NN + 1 + j];
        const float v = s / 12.0f;
        cls32[b * 576 + j] = v;
        out_cls[b * 576 + j] = v;
    }
}

// rank-counting top-k: rank(i) = #{j : v_j > v_i || (v_j == v_i && j < i)}
// Strict total order (stable on exact fp32 ties) -> bijection -> direct write.
__global__ __launch_bounds__(256) void topk_rank(const float* __restrict__ cls32,
                                                 float* __restrict__ out_idx,
                                                 int* __restrict__ idxi)
{
    const int b = blockIdx.x;
    const int t = threadIdx.x;
    __shared__ float sv[576];
    for (int i = t; i < 576; i += 256) sv[i] = cls32[b * 576 + i];
    __syncthreads();
    for (int i = t; i < 576; i += 256) {
        const float vi = sv[i];
        int rank = 0;
        for (int j = 0; j < 576; ++j) {
            const float vj = sv[j];
            if (vj > vi || (vj == vi && j < i)) ++rank;
        }
        if (rank < LEFT) {
            out_idx[(size_t)b * LEFT + rank] = (float)i;
            idxi[(size_t)b * LEFT + rank] = i;
        }
    }
}

__global__ void write_index(const int* __restrict__ idxi, float* __restrict__ out_index)
{
    const int g = blockIdx.x * 256 + threadIdx.x;
    if (g < BB * LEFT * CC) out_index[g] = (float)idxi[g / CC];
}

// ---------------------------------------------------------------------------
extern "C" void kernel_launch(void* const* d_in, const int* in_sizes, int n_in,
                              void* d_out, int out_size, void* d_ws, size_t ws_size,
                              hipStream_t stream)
{
    const float* x      = (const float*)d_in[0];
    const float* qkv_w  = (const float*)d_in[1];
    const float* proj_w = (const float*)d_in[2];
    const float* proj_b = (const float*)d_in[3];
    float* out = (float*)d_out;

    // ws layout
    float* qb = (float*)d_ws;                       // [B][H][N][HD]  17.0 MB
    float* kb = qb + (size_t)BB*HH*NN*HD;
    float* vb = kb + (size_t)BB*HH*NN*HD;
    float* ao = vb + (size_t)BB*HH*NN*HD;           // [B][N][C]      28.4 MB
    // cls scratch after ao (region validated in round 1)
    float* P     = (float*)((char*)d_ws + 113442816ULL);  // [192][577] fp32
    float* cls32 = P + (size_t)BB*HH*NN;                  // [16][576]
    int*   idxi  = (int*)(cls32 + (size_t)BB*576);        // [16][404]

    float* out_main  = out;                 // 7,090,176
    float* out_idx   = out + 7090176;       // 6,464
    float* out_index = out + 7096640;       // 4,964,352
    float* out_cls   = out + 12060992;      // 9,216

    qkv_gemm<<<dim3(73, 18), 256, 0, stream>>>(x, qkv_w, qb, kb, vb);
    attn_kernel<<<BB * HH * NTILE, 256, 0, stream>>>(qb, kb, vb, ao);
    proj_gemm<<<dim3(73, 6), 256, 0, stream>>>(ao, proj_w, proj_b, out_main);

    cls_scores<<<BB * HH, 256, 0, stream>>>(qb, kb, P);
    cls_mean32<<<BB, 256, 0, stream>>>(P, cls32, out_cls);
    topk_rank<<<BB, 256, 0, stream>>>(cls32, out_idx, idxi);
    write_index<<<(BB * LEFT * CC) / 256, 256, 0, stream>>>(idxi, out_index);
}

// Round 4
// 826.730 us; speedup vs baseline: 2.2517x; 2.2517x over previous
//
#include <hip/hip_runtime.h>
#include <math.h>

#define BB 16
#define NN 577
#define CC 768
#define HH 12
#define HD 64
#define MM (BB*NN)      // 9232
#define LEFT 404
#define NPAD 608        // padded key count (19 chunks of 32)
#define NQT 10          // ceil(577/64) q-tiles of 64

typedef __attribute__((ext_vector_type(8))) short short8v;   // 8 bf16
typedef __attribute__((ext_vector_type(4))) float f32x4;

__device__ __forceinline__ unsigned short f2bf(float f) {
    union { float f; unsigned int u; } v; v.f = f;
    unsigned int r = v.u + 0x7fffu + ((v.u >> 16) & 1u);   // RNE
    return (unsigned short)(r >> 16);
}

// ---------------------------------------------------------------------------
// QKV GEMM: qkv[i, col] = sum_k X[i,k] * W[col,k]
// q,k -> fp32 (cls path depends on these bit-exactly; UNCHANGED math)
// k   -> also bf16 copy kbh [bh][608][64]
// v   -> bf16 transposed Vt [bh][64][608]   (fp32 vb eliminated)
// ---------------------------------------------------------------------------
__global__ __launch_bounds__(256) void qkv_gemm(const float* __restrict__ X,
                                                const float* __restrict__ W,
                                                float* __restrict__ qb,
                                                float* __restrict__ kb,
                                                unsigned short* __restrict__ kbh,
                                                unsigned short* __restrict__ Vt)
{
    __shared__ float Xs[16][128];
    __shared__ float Ws[16][128];
    const int t  = threadIdx.x;
    const int tx = t & 15, ty = t >> 4;
    const int m0 = blockIdx.x * 128;
    const int n0 = blockIdx.y * 128;
    const int sm = t & 127;
    const int sk = (t >> 7) * 8;

    float acc[8][8];
    #pragma unroll
    for (int i = 0; i < 8; ++i)
        #pragma unroll
        for (int j = 0; j < 8; ++j) acc[i][j] = 0.f;

    for (int kk = 0; kk < CC; kk += 16) {
        {
            const int gm = m0 + sm;
            float4 a0 = make_float4(0.f,0.f,0.f,0.f), a1 = a0;
            if (gm < MM) {
                const float* p = X + (size_t)gm * CC + kk + sk;
                a0 = *(const float4*)p;
                a1 = *(const float4*)(p + 4);
            }
            Xs[sk+0][sm] = a0.x; Xs[sk+1][sm] = a0.y; Xs[sk+2][sm] = a0.z; Xs[sk+3][sm] = a0.w;
            Xs[sk+4][sm] = a1.x; Xs[sk+5][sm] = a1.y; Xs[sk+6][sm] = a1.z; Xs[sk+7][sm] = a1.w;
            const float* pw = W + (size_t)(n0 + sm) * CC + kk + sk;
            float4 b0 = *(const float4*)pw;
            float4 b1 = *(const float4*)(pw + 4);
            Ws[sk+0][sm] = b0.x; Ws[sk+1][sm] = b0.y; Ws[sk+2][sm] = b0.z; Ws[sk+3][sm] = b0.w;
            Ws[sk+4][sm] = b1.x; Ws[sk+5][sm] = b1.y; Ws[sk+6][sm] = b1.z; Ws[sk+7][sm] = b1.w;
        }
        __syncthreads();
        #pragma unroll
        for (int k = 0; k < 16; ++k) {
            float a[8], bv[8];
            *(float4*)&a[0]  = *(const float4*)&Xs[k][ty*8];
            *(float4*)&a[4]  = *(const float4*)&Xs[k][ty*8+4];
            *(float4*)&bv[0] = *(const float4*)&Ws[k][tx*8];
            *(float4*)&bv[4] = *(const float4*)&Ws[k][tx*8+4];
            #pragma unroll
            for (int i = 0; i < 8; ++i)
                #pragma unroll
                for (int j = 0; j < 8; ++j)
                    acc[i][j] = fmaf(a[i], bv[j], acc[i][j]);
        }
        __syncthreads();
    }
    const int which = n0 / CC;          // uniform per block
    #pragma unroll
    for (int i = 0; i < 8; ++i) {
        const int gm = m0 + ty*8 + i;
        if (gm >= MM) continue;
        const int b_ = gm / NN;
        const int n_ = gm - b_ * NN;
        #pragma unroll
        for (int j = 0; j < 8; ++j) {
            const int col = n0 + tx*8 + j - which * CC;   // 0..767
            const int h = col >> 6, d = col & 63;
            const size_t bh = (size_t)b_ * HH + h;
            const float a = acc[i][j];
            if (which == 0) {
                qb[(bh * NN + n_) * HD + d] = a;
            } else if (which == 1) {
                kb[(bh * NN + n_) * HD + d] = a;
                kbh[(bh * NPAD + n_) * HD + d] = f2bf(a);
            } else {
                Vt[(bh * HD + d) * NPAD + n_] = f2bf(a);
            }
        }
    }
}

// ---------------------------------------------------------------------------
// proj GEMM: out[i,j] = sum_k A[i,k] * W[j,k] + bias[j]   [unchanged]
// ---------------------------------------------------------------------------
__global__ __launch_bounds__(256) void proj_gemm(const float* __restrict__ A,
                                                 const float* __restrict__ W,
                                                 const float* __restrict__ bias,
                                                 float* __restrict__ out)
{
    __shared__ float As[16][128];
    __shared__ float Ws[16][128];
    const int t  = threadIdx.x;
    const int tx = t & 15, ty = t >> 4;
    const int m0 = blockIdx.x * 128;
    const int n0 = blockIdx.y * 128;
    const int sm = t & 127;
    const int sk = (t >> 7) * 8;

    float acc[8][8];
    #pragma unroll
    for (int i = 0; i < 8; ++i)
        #pragma unroll
        for (int j = 0; j < 8; ++j) acc[i][j] = 0.f;

    for (int kk = 0; kk < CC; kk += 16) {
        {
            const int gm = m0 + sm;
            float4 a0 = make_float4(0.f,0.f,0.f,0.f), a1 = a0;
            if (gm < MM) {
                const float* p = A + (size_t)gm * CC + kk + sk;
                a0 = *(const float4*)p;
                a1 = *(const float4*)(p + 4);
            }
            As[sk+0][sm] = a0.x; As[sk+1][sm] = a0.y; As[sk+2][sm] = a0.z; As[sk+3][sm] = a0.w;
            As[sk+4][sm] = a1.x; As[sk+5][sm] = a1.y; As[sk+6][sm] = a1.z; As[sk+7][sm] = a1.w;
            const float* pw = W + (size_t)(n0 + sm) * CC + kk + sk;
            float4 b0 = *(const float4*)pw;
            float4 b1 = *(const float4*)(pw + 4);
            Ws[sk+0][sm] = b0.x; Ws[sk+1][sm] = b0.y; Ws[sk+2][sm] = b0.z; Ws[sk+3][sm] = b0.w;
            Ws[sk+4][sm] = b1.x; Ws[sk+5][sm] = b1.y; Ws[sk+6][sm] = b1.z; Ws[sk+7][sm] = b1.w;
        }
        __syncthreads();
        #pragma unroll
        for (int k = 0; k < 16; ++k) {
            float a[8], bv[8];
            *(float4*)&a[0]  = *(const float4*)&As[k][ty*8];
            *(float4*)&a[4]  = *(const float4*)&As[k][ty*8+4];
            *(float4*)&bv[0] = *(const float4*)&Ws[k][tx*8];
            *(float4*)&bv[4] = *(const float4*)&Ws[k][tx*8+4];
            #pragma unroll
            for (int i = 0; i < 8; ++i)
                #pragma unroll
                for (int j = 0; j < 8; ++j)
                    acc[i][j] = fmaf(a[i], bv[j], acc[i][j]);
        }
        __syncthreads();
    }
    #pragma unroll
    for (int i = 0; i < 8; ++i) {
        const int gm = m0 + ty*8 + i;
        if (gm >= MM) continue;
        #pragma unroll
        for (int j = 0; j < 8; ++j) {
            const int col = n0 + tx*8 + j;
            out[(size_t)gm * CC + col] = acc[i][j] + bias[col];
        }
    }
}

// ---------------------------------------------------------------------------
// MFMA flash attention. Block = 4 waves, 64 Q rows per block (16/wave).
// Online softmax over 19 key-chunks of 32. P relayout via per-wave LDS.
// A-frag: lane holds M[row=l&15][k=8*(l>>4)+i]; B-frag: B[k=8*(l>>4)+i][col=l&15];
// C/D: col=l&15, row=4*(l>>4)+reg  (guide-verified layout).
// ---------------------------------------------------------------------------
__global__ __launch_bounds__(256) void attn_mfma(const float* __restrict__ qb,
                                                 const unsigned short* __restrict__ kbh,
                                                 const unsigned short* __restrict__ Vt,
                                                 float* __restrict__ ao)
{
    __shared__ __align__(16) unsigned short plds[4][16][32];
    const int bid = blockIdx.x;
    const int bh  = bid / NQT;
    const int qt  = bid - bh * NQT;
    const int b   = bh / HH, h = bh - b * HH;
    const int t   = threadIdx.x;
    const int w   = t >> 6, l = t & 63;
    const int l15 = l & 15, lg = l >> 4;

    // Q A-frags (convert fp32 -> bf16 in-register), rows clamped (masked on store)
    short8v aq0, aq1;
    {
        int qrow = qt*64 + w*16 + l15; if (qrow > 576) qrow = 576;
        const float* qp = qb + ((size_t)bh * NN + qrow) * HD + lg*8;
        float4 f0 = *(const float4*)(qp);
        float4 f1 = *(const float4*)(qp + 4);
        float4 f2 = *(const float4*)(qp + 32);
        float4 f3 = *(const float4*)(qp + 36);
        aq0[0]=(short)f2bf(f0.x); aq0[1]=(short)f2bf(f0.y); aq0[2]=(short)f2bf(f0.z); aq0[3]=(short)f2bf(f0.w);
        aq0[4]=(short)f2bf(f1.x); aq0[5]=(short)f2bf(f1.y); aq0[6]=(short)f2bf(f1.z); aq0[7]=(short)f2bf(f1.w);
        aq1[0]=(short)f2bf(f2.x); aq1[1]=(short)f2bf(f2.y); aq1[2]=(short)f2bf(f2.z); aq1[3]=(short)f2bf(f2.w);
        aq1[4]=(short)f2bf(f3.x); aq1[5]=(short)f2bf(f3.y); aq1[6]=(short)f2bf(f3.z); aq1[7]=(short)f2bf(f3.w);
    }

    f32x4 O0 = {0.f,0.f,0.f,0.f}, O1 = O0, O2 = O0, O3 = O0;
    float mr[4] = {-1e30f,-1e30f,-1e30f,-1e30f};
    float lr[4] = {0.f,0.f,0.f,0.f};

    const unsigned short* kwb = kbh + (size_t)bh * NPAD * HD + (size_t)l15 * HD + lg*8;
    const unsigned short* vwb = Vt  + (size_t)bh * HD * NPAD + (size_t)l15 * NPAD + lg*8;

    for (int c = 0; c < 19; ++c) {
        const int n0 = c * 32;
        // --- QK^T: two 16-key subtiles, k = 64 in two mfma steps each
        const unsigned short* kp = kwb + (size_t)n0 * HD;
        short8v bk00 = *(const short8v*)(kp);
        short8v bk01 = *(const short8v*)(kp + 32);
        short8v bk10 = *(const short8v*)(kp + 16*HD);
        short8v bk11 = *(const short8v*)(kp + 16*HD + 32);
        f32x4 s0 = {0.f,0.f,0.f,0.f}, s1 = {0.f,0.f,0.f,0.f};
        s0 = __builtin_amdgcn_mfma_f32_16x16x32_bf16(aq0, bk00, s0, 0, 0, 0);
        s0 = __builtin_amdgcn_mfma_f32_16x16x32_bf16(aq1, bk01, s0, 0, 0, 0);
        s1 = __builtin_amdgcn_mfma_f32_16x16x32_bf16(aq0, bk10, s1, 0, 0, 0);
        s1 = __builtin_amdgcn_mfma_f32_16x16x32_bf16(aq1, bk11, s1, 0, 0, 0);

        const int nc0 = n0 + l15;
        float p0[4], p1[4], al[4];
        #pragma unroll
        for (int r = 0; r < 4; ++r) {
            float a0 = (nc0      <= 576) ? s0[r] * 0.125f : -1e30f;
            float a1 = (nc0 + 16 <= 576) ? s1[r] * 0.125f : -1e30f;
            float tm = fmaxf(a0, a1);
            tm = fmaxf(tm, __shfl_xor(tm, 1, 64));
            tm = fmaxf(tm, __shfl_xor(tm, 2, 64));
            tm = fmaxf(tm, __shfl_xor(tm, 4, 64));
            tm = fmaxf(tm, __shfl_xor(tm, 8, 64));
            const float mn = fmaxf(mr[r], tm);
            al[r] = __expf(mr[r] - mn);
            mr[r] = mn;
            p0[r] = __expf(a0 - mn);
            p1[r] = __expf(a1 - mn);
            float ps = p0[r] + p1[r];
            ps += __shfl_xor(ps, 1, 64);
            ps += __shfl_xor(ps, 2, 64);
            ps += __shfl_xor(ps, 4, 64);
            ps += __shfl_xor(ps, 8, 64);
            lr[r] = lr[r] * al[r] + ps;
        }
        #pragma unroll
        for (int r = 0; r < 4; ++r) {
            O0[r] *= al[r]; O1[r] *= al[r]; O2[r] *= al[r]; O3[r] *= al[r];
        }
        // --- P: C-layout regs -> A-layout frag via per-wave-private LDS bounce
        #pragma unroll
        for (int r = 0; r < 4; ++r) {
            plds[w][lg*4 + r][l15]      = f2bf(p0[r]);
            plds[w][lg*4 + r][16 + l15] = f2bf(p1[r]);
        }
        asm volatile("s_waitcnt lgkmcnt(0)" ::: "memory");
        short8v pa = *(const short8v*)&plds[w][l15][lg*8];
        // --- PV: 4 d-tiles, k = 32 keys
        const unsigned short* vp = vwb + n0;
        short8v v0 = *(const short8v*)(vp);
        short8v v1 = *(const short8v*)(vp + 16*NPAD);
        short8v v2 = *(const short8v*)(vp + 32*NPAD);
        short8v v3 = *(const short8v*)(vp + 48*NPAD);
        O0 = __builtin_amdgcn_mfma_f32_16x16x32_bf16(pa, v0, O0, 0, 0, 0);
        O1 = __builtin_amdgcn_mfma_f32_16x16x32_bf16(pa, v1, O1, 0, 0, 0);
        O2 = __builtin_amdgcn_mfma_f32_16x16x32_bf16(pa, v2, O2, 0, 0, 0);
        O3 = __builtin_amdgcn_mfma_f32_16x16x32_bf16(pa, v3, O3, 0, 0, 0);
    }

    // epilogue: normalize + store (row = 4*lg + r, col = dt*16 + l15)
    #pragma unroll
    for (int r = 0; r < 4; ++r) {
        const float inv = 1.f / lr[r];
        const int row = qt*64 + w*16 + lg*4 + r;
        if (row <= 576) {
            float* op = ao + ((size_t)b * NN + row) * CC + h*HD + l15;
            op[0]  = O0[r] * inv;
            op[16] = O1[r] * inv;
            op[32] = O2[r] * inv;
            op[48] = O3[r] * inv;
        }
    }
}

// ---------------------------------------------------------------------------
// CLS path — UNCHANGED from round 3 (bit-exact; idx passed with these numerics)
// ---------------------------------------------------------------------------
__global__ __launch_bounds__(256) void cls_scores(const float* __restrict__ qb,
                                                  const float* __restrict__ kb,
                                                  float* __restrict__ P)
{
    const int bh = blockIdx.x;
    const int t = threadIdx.x;
    __shared__ float q[64];
    __shared__ float red[256];
    __shared__ float L[NN];
    if (t < 64) q[t] = qb[(size_t)bh * NN * HD + t];   // q row 0 (CLS)
    __syncthreads();
    float lmax = -1e30f;
    for (int n = t; n < NN; n += 256) {
        const float* kr = kb + ((size_t)bh * NN + n) * HD;
        float acc = 0.f;
        #pragma unroll
        for (int d = 0; d < 64; ++d) acc = fmaf(q[d], kr[d], acc);
        const float l = acc * 0.125f;
        L[n] = l;
        lmax = fmaxf(lmax, l);
    }
    red[t] = lmax; __syncthreads();
    for (int s = 128; s > 0; s >>= 1) { if (t < s) red[t] = fmaxf(red[t], red[t+s]); __syncthreads(); }
    const float m = red[0]; __syncthreads();
    float z = 0.f;
    for (int n = t; n < NN; n += 256) { const float e = expf(L[n] - m); L[n] = e; z += e; }
    red[t] = z; __syncthreads();
    for (int s = 128; s > 0; s >>= 1) { if (t < s) red[t] += red[t+s]; __syncthreads(); }
    const float Z = red[0];
    for (int n = t; n < NN; n += 256) P[(size_t)bh * NN + n] = L[n] / Z;
}

__global__ __launch_bounds__(256) void cls_mean32(const float* __restrict__ P,
                                                  float* __restrict__ cls32,
                                                  float* __restrict__ out_cls)
{
    const int b = blockIdx.x;
    for (int j = threadIdx.x; j < NN - 1; j += 256) {
        float s = 0.f;
        #pragma unroll
        for (int h = 0; h < HH; ++h) s += P[((size_t)(b * HH + h)) * NN + 1 + j];
        const float v = s / 12.0f;
        cls32[b * 576 + j] = v;
        out_cls[b * 576 + j] = v;
    }
}

__global__ __launch_bounds__(256) void topk_rank(const float* __restrict__ cls32,
                                                 float* __restrict__ out_idx,
                                                 int* __restrict__ idxi)
{
    const int b = blockIdx.x;
    const int t = threadIdx.x;
    __shared__ float sv[576];
    for (int i = t; i < 576; i += 256) sv[i] = cls32[b * 576 + i];
    __syncthreads();
    for (int i = t; i < 576; i += 256) {
        const float vi = sv[i];
        int rank = 0;
        for (int j = 0; j < 576; ++j) {
            const float vj = sv[j];
            if (vj > vi || (vj == vi && j < i)) ++rank;
        }
        if (rank < LEFT) {
            out_idx[(size_t)b * LEFT + rank] = (float)i;
            idxi[(size_t)b * LEFT + rank] = i;
        }
    }
}

__global__ void write_index(const int* __restrict__ idxi, float* __restrict__ out_index)
{
    const int g = blockIdx.x * 256 + threadIdx.x;
    if (g < BB * LEFT * CC) out_index[g] = (float)idxi[g / CC];
}

// ---------------------------------------------------------------------------
extern "C" void kernel_launch(void* const* d_in, const int* in_sizes, int n_in,
                              void* d_out, int out_size, void* d_ws, size_t ws_size,
                              hipStream_t stream)
{
    const float* x      = (const float*)d_in[0];
    const float* qkv_w  = (const float*)d_in[1];
    const float* proj_w = (const float*)d_in[2];
    const float* proj_b = (const float*)d_in[3];
    float* out = (float*)d_out;

    // ws layout (total 114,966,528 B — within the 115.6 MB region proven in R1)
    float* qb = (float*)d_ws;                                    // [bh][577][64] f32  28,360,704 B
    float* kb = qb + (size_t)BB*HH*NN*HD;                        // same               28,360,704 B
    float* ao = kb + (size_t)BB*HH*NN*HD;                        // [B][577][768] f32  28,360,704 B
    unsigned short* Vt  = (unsigned short*)((char*)d_ws + 85082112ULL);   // [bh][64][608] bf16 14,942,208 B
    unsigned short* kbh = (unsigned short*)((char*)d_ws + 100024320ULL);  // [bh][608][64] bf16 14,942,208 B

    // cls scratch overlays Vt region (Vt dead after attn; cls runs after)
    float* P     = (float*)((char*)d_ws + 85082112ULL);          // [192][577] f32
    float* cls32 = P + (size_t)BB*HH*NN;                         // [16][576]
    int*   idxi  = (int*)(cls32 + (size_t)BB*576);               // [16][404]

    float* out_main  = out;                 // 7,090,176
    float* out_idx   = out + 7090176;       // 6,464
    float* out_index = out + 7096640;       // 4,964,352
    float* out_cls   = out + 12060992;      // 9,216

    // zero Vt + kbh (covers the n>=577 padding rows/cols)
    hipMemsetAsync((char*)d_ws + 85082112ULL, 0, 29884416ULL, stream);

    qkv_gemm<<<dim3(73, 18), 256, 0, stream>>>(x, qkv_w, qb, kb, kbh, Vt);
    attn_mfma<<<BB * HH * NQT, 256, 0, stream>>>(qb, kbh, Vt, ao);
    proj_gemm<<<dim3(73, 6), 256, 0, stream>>>(ao, proj_w, proj_b, out_main);

    cls_scores<<<BB * HH, 256, 0, stream>>>(qb, kb, P);
    cls_mean32<<<BB, 256, 0, stream>>>(P, cls32, out_cls);
    topk_rank<<<BB, 256, 0, stream>>>(cls32, out_idx, idxi);
    write_index<<<(BB * LEFT * CC) / 256, 256, 0, stream>>>(idxi, out_index);
}

// Round 5
// 445.800 us; speedup vs baseline: 4.1757x; 1.8545x over previous
//
#include <hip/hip_runtime.h>
#include <math.h>

#define BB 16
#define NN 577
#define CC 768
#define HH 12
#define HD 64
#define MM (BB*NN)      // 9232
#define MPAD 9344       // 73*128
#define LEFT 404
#define NPAD 608        // padded token count (19 chunks of 32)
#define NQT 10          // ceil(577/64) q-tiles of 64

typedef __attribute__((ext_vector_type(8))) short short8v;   // 8 bf16
typedef __attribute__((ext_vector_type(4))) float f32x4;

__device__ __forceinline__ unsigned short f2bf(float f) {
    union { float f; unsigned int u; } v; v.f = f;
    unsigned int r = v.u + 0x7fffu + ((v.u >> 16) & 1u);   // RNE
    return (unsigned short)(r >> 16);
}

// ---------------------------------------------------------------------------
// Exact fp32 K-GEMM (bit-identical inner loop to the validated qkv_gemm,
// narrowed to the K third). Writes kb (fp32, cls path) + kbh (bf16, attn).
// ---------------------------------------------------------------------------
__global__ __launch_bounds__(256) void k_gemm_fp32(const float* __restrict__ X,
                                                   const float* __restrict__ W,
                                                   float* __restrict__ kb,
                                                   unsigned short* __restrict__ kbh)
{
    __shared__ float Xs[16][128];
    __shared__ float Ws[16][128];
    const int t  = threadIdx.x;
    const int tx = t & 15, ty = t >> 4;
    const int m0 = blockIdx.x * 128;
    const int n0 = 768 + blockIdx.y * 128;     // K columns of W
    const int sm = t & 127;
    const int sk = (t >> 7) * 8;

    float acc[8][8];
    #pragma unroll
    for (int i = 0; i < 8; ++i)
        #pragma unroll
        for (int j = 0; j < 8; ++j) acc[i][j] = 0.f;

    for (int kk = 0; kk < CC; kk += 16) {
        {
            const int gm = m0 + sm;
            float4 a0 = make_float4(0.f,0.f,0.f,0.f), a1 = a0;
            if (gm < MM) {
                const float* p = X + (size_t)gm * CC + kk + sk;
                a0 = *(const float4*)p;
                a1 = *(const float4*)(p + 4);
            }
            Xs[sk+0][sm] = a0.x; Xs[sk+1][sm] = a0.y; Xs[sk+2][sm] = a0.z; Xs[sk+3][sm] = a0.w;
            Xs[sk+4][sm] = a1.x; Xs[sk+5][sm] = a1.y; Xs[sk+6][sm] = a1.z; Xs[sk+7][sm] = a1.w;
            const float* pw = W + (size_t)(n0 + sm) * CC + kk + sk;
            float4 b0 = *(const float4*)pw;
            float4 b1 = *(const float4*)(pw + 4);
            Ws[sk+0][sm] = b0.x; Ws[sk+1][sm] = b0.y; Ws[sk+2][sm] = b0.z; Ws[sk+3][sm] = b0.w;
            Ws[sk+4][sm] = b1.x; Ws[sk+5][sm] = b1.y; Ws[sk+6][sm] = b1.z; Ws[sk+7][sm] = b1.w;
        }
        __syncthreads();
        #pragma unroll
        for (int k = 0; k < 16; ++k) {
            float a[8], bv[8];
            *(float4*)&a[0]  = *(const float4*)&Xs[k][ty*8];
            *(float4*)&a[4]  = *(const float4*)&Xs[k][ty*8+4];
            *(float4*)&bv[0] = *(const float4*)&Ws[k][tx*8];
            *(float4*)&bv[4] = *(const float4*)&Ws[k][tx*8+4];
            #pragma unroll
            for (int i = 0; i < 8; ++i)
                #pragma unroll
                for (int j = 0; j < 8; ++j)
                    acc[i][j] = fmaf(a[i], bv[j], acc[i][j]);
        }
        __syncthreads();
    }
    #pragma unroll
    for (int i = 0; i < 8; ++i) {
        const int gm = m0 + ty*8 + i;
        if (gm >= MM) continue;
        const int b_ = gm / NN;
        const int n_ = gm - b_ * NN;
        #pragma unroll
        for (int j = 0; j < 8; ++j) {
            const int col = n0 + tx*8 + j - 768;          // 0..767
            const int h = col >> 6, d = col & 63;
            const float a = acc[i][j];
            kb [(((size_t)b_ * HH + h) * NN   + n_) * HD + d] = a;
            kbh[(((size_t)b_ * HH + h) * NPAD + n_) * HD + d] = f2bf(a);
        }
    }
}

// ---------------------------------------------------------------------------
// Exact fp32 q_cls (row 0 per (b,h)) — ascending-k fmaf, bit-identical to the
// old tiled GEMM's reduction for row 0. qcls[b][col], col = h*64+d.
// ---------------------------------------------------------------------------
__global__ __launch_bounds__(256) void qcls_kernel(const float* __restrict__ X,
                                                   const float* __restrict__ W,
                                                   float* __restrict__ qcls)
{
    const int b = blockIdx.x;
    const int col = blockIdx.y * 256 + threadIdx.x;   // 0..767
    const float* xr = X + (size_t)b * NN * CC;        // CLS row
    const float* wr = W + (size_t)col * CC;
    float acc = 0.f;
    for (int k = 0; k < CC; ++k) acc = fmaf(xr[k], wr[k], acc);
    qcls[(size_t)b * CC + col] = acc;
}

// ---------------------------------------------------------------------------
// fp32 -> bf16 conversions (x, qkv_w, proj_w) in one launch
// ---------------------------------------------------------------------------
#define N4X 1772544   // 9232*768/4
#define N4W 442368    // 2304*768/4
#define N4P 147456    // 768*768/4
__global__ __launch_bounds__(256) void convert3(const float* __restrict__ x,
                                                const float* __restrict__ wq,
                                                const float* __restrict__ wp,
                                                unsigned short* __restrict__ xb,
                                                unsigned short* __restrict__ wqb,
                                                unsigned short* __restrict__ wpb)
{
    int g = blockIdx.x * 256 + threadIdx.x;
    const float* src; unsigned short* dst;
    if (g < N4X)            { src = x;  dst = xb;  }
    else if (g < N4X + N4W) { g -= N4X; src = wq; dst = wqb; }
    else                    { g -= (N4X + N4W); src = wp; dst = wpb; }
    const float4 v = ((const float4*)src)[g];
    ushort4 o;
    o.x = f2bf(v.x); o.y = f2bf(v.y); o.z = f2bf(v.z); o.w = f2bf(v.w);
    ((ushort4*)dst)[g] = o;
}

// ---------------------------------------------------------------------------
// bf16 MFMA GEMM (C = A * B^T), 128x128 tile, 4 waves in 2x2, 4x4 16x16 frags.
// Q/V variant: A = xbh [MPAD][768], B = wqkv rows; writes qbh / Vt (bf16).
// ---------------------------------------------------------------------------
__global__ __launch_bounds__(256) void qv_mfma(const unsigned short* __restrict__ xbh,
                                               const unsigned short* __restrict__ wqkv,
                                               unsigned short* __restrict__ qbh,
                                               unsigned short* __restrict__ Vt)
{
    __shared__ unsigned short As[128*32];
    __shared__ unsigned short Bs[128*32];
    const int t = threadIdx.x;
    const int w = t >> 6, l = t & 63;
    const int l15 = l & 15, lk = l >> 4;
    const int wm = w >> 1, wn = w & 1;
    const int m0 = blockIdx.x * 128;
    const int isV = blockIdx.y >= 6;
    const int nlocal0 = (isV ? (blockIdx.y - 6) : blockIdx.y) * 128;
    const int wrow0 = (isV ? 1536 : 0) + nlocal0;
    const int r0 = t >> 2, segp = t & 3;

    f32x4 acc[4][4];
    #pragma unroll
    for (int i = 0; i < 4; ++i)
        #pragma unroll
        for (int j = 0; j < 4; ++j) acc[i][j] = (f32x4){0.f,0.f,0.f,0.f};

    const unsigned short* ga = xbh  + (size_t)(m0 + r0) * CC + segp * 8;
    const unsigned short* gb = wqkv + (size_t)(wrow0 + r0) * CC + segp * 8;

    for (int kk = 0; kk < CC; kk += 32) {
        const short8v a0 = *(const short8v*)(ga + kk);
        const short8v a1 = *(const short8v*)(ga + kk + (size_t)64 * CC);
        const short8v b0 = *(const short8v*)(gb + kk);
        const short8v b1 = *(const short8v*)(gb + kk + (size_t)64 * CC);
        __syncthreads();
        *(short8v*)&As[(r0)      * 32 + segp*8] = a0;
        *(short8v*)&As[(64 + r0) * 32 + segp*8] = a1;
        *(short8v*)&Bs[(r0)      * 32 + segp*8] = b0;
        *(short8v*)&Bs[(64 + r0) * 32 + segp*8] = b1;
        __syncthreads();
        short8v fa[4], fb[4];
        #pragma unroll
        for (int i = 0; i < 4; ++i) fa[i] = *(const short8v*)&As[(wm*64 + i*16 + l15)*32 + lk*8];
        #pragma unroll
        for (int j = 0; j < 4; ++j) fb[j] = *(const short8v*)&Bs[(wn*64 + j*16 + l15)*32 + lk*8];
        #pragma unroll
        for (int i = 0; i < 4; ++i)
            #pragma unroll
            for (int j = 0; j < 4; ++j)
                acc[i][j] = __builtin_amdgcn_mfma_f32_16x16x32_bf16(fa[i], fb[j], acc[i][j], 0, 0, 0);
    }

    const int nb = nlocal0 + wn*64 + l15;
    #pragma unroll
    for (int i = 0; i < 4; ++i) {
        #pragma unroll
        for (int r = 0; r < 4; ++r) {
            const int m = m0 + wm*64 + i*16 + 4*lk + r;
            if (m >= MM) continue;
            const int b_ = m / NN, tok = m - b_ * NN;
            #pragma unroll
            for (int j = 0; j < 4; ++j) {
                const int nl = nb + j*16;
                const int h = nl >> 6, d = nl & 63;
                const unsigned short v = f2bf(acc[i][j][r]);
                if (isV) Vt [(((size_t)b_*HH + h)*HD + d)*NPAD + tok] = v;
                else     qbh[(((size_t)b_*HH + h)*NPAD + tok)*HD + d] = v;
            }
        }
    }
}

// proj variant: A = aobh [MPAD][768] bf16, B = wpb [768][768] bf16; out fp32+bias
__global__ __launch_bounds__(256) void proj_mfma(const unsigned short* __restrict__ aobh,
                                                 const unsigned short* __restrict__ wpb,
                                                 const float* __restrict__ bias,
                                                 float* __restrict__ outp)
{
    __shared__ unsigned short As[128*32];
    __shared__ unsigned short Bs[128*32];
    const int t = threadIdx.x;
    const int w = t >> 6, l = t & 63;
    const int l15 = l & 15, lk = l >> 4;
    const int wm = w >> 1, wn = w & 1;
    const int m0 = blockIdx.x * 128;
    const int n0 = blockIdx.y * 128;
    const int r0 = t >> 2, segp = t & 3;

    f32x4 acc[4][4];
    #pragma unroll
    for (int i = 0; i < 4; ++i)
        #pragma unroll
        for (int j = 0; j < 4; ++j) acc[i][j] = (f32x4){0.f,0.f,0.f,0.f};

    const unsigned short* ga = aobh + (size_t)(m0 + r0) * CC + segp * 8;
    const unsigned short* gb = wpb  + (size_t)(n0 + r0) * CC + segp * 8;

    for (int kk = 0; kk < CC; kk += 32) {
        const short8v a0 = *(const short8v*)(ga + kk);
        const short8v a1 = *(const short8v*)(ga + kk + (size_t)64 * CC);
        const short8v b0 = *(const short8v*)(gb + kk);
        const short8v b1 = *(const short8v*)(gb + kk + (size_t)64 * CC);
        __syncthreads();
        *(short8v*)&As[(r0)      * 32 + segp*8] = a0;
        *(short8v*)&As[(64 + r0) * 32 + segp*8] = a1;
        *(short8v*)&Bs[(r0)      * 32 + segp*8] = b0;
        *(short8v*)&Bs[(64 + r0) * 32 + segp*8] = b1;
        __syncthreads();
        short8v fa[4], fb[4];
        #pragma unroll
        for (int i = 0; i < 4; ++i) fa[i] = *(const short8v*)&As[(wm*64 + i*16 + l15)*32 + lk*8];
        #pragma unroll
        for (int j = 0; j < 4; ++j) fb[j] = *(const short8v*)&Bs[(wn*64 + j*16 + l15)*32 + lk*8];
        #pragma unroll
        for (int i = 0; i < 4; ++i)
            #pragma unroll
            for (int j = 0; j < 4; ++j)
                acc[i][j] = __builtin_amdgcn_mfma_f32_16x16x32_bf16(fa[i], fb[j], acc[i][j], 0, 0, 0);
    }

    const int nb = n0 + wn*64 + l15;
    #pragma unroll
    for (int i = 0; i < 4; ++i) {
        #pragma unroll
        for (int r = 0; r < 4; ++r) {
            const int m = m0 + wm*64 + i*16 + 4*lk + r;
            if (m >= MM) continue;
            #pragma unroll
            for (int j = 0; j < 4; ++j) {
                const int n = nb + j*16;
                outp[(size_t)m * CC + n] = acc[i][j][r] + bias[n];
            }
        }
    }
}

// ---------------------------------------------------------------------------
// MFMA flash attention (validated R4), now bf16 in (qbh) / bf16 out (aobh)
// ---------------------------------------------------------------------------
__global__ __launch_bounds__(256) void attn_mfma(const unsigned short* __restrict__ qbh,
                                                 const unsigned short* __restrict__ kbh,
                                                 const unsigned short* __restrict__ Vt,
                                                 unsigned short* __restrict__ aobh)
{
    __shared__ __align__(16) unsigned short plds[4][16][32];
    const int bid = blockIdx.x;
    const int bh  = bid / NQT;
    const int qt  = bid - bh * NQT;
    const int b   = bh / HH, h = bh - b * HH;
    const int t   = threadIdx.x;
    const int w   = t >> 6, l = t & 63;
    const int l15 = l & 15, lg = l >> 4;

    short8v aq0, aq1;
    {
        int qrow = qt*64 + w*16 + l15; if (qrow > 576) qrow = 576;
        const unsigned short* qp = qbh + ((size_t)bh * NPAD + qrow) * HD + lg*8;
        aq0 = *(const short8v*)(qp);
        aq1 = *(const short8v*)(qp + 32);
    }

    f32x4 O0 = {0.f,0.f,0.f,0.f}, O1 = O0, O2 = O0, O3 = O0;
    float mr[4] = {-1e30f,-1e30f,-1e30f,-1e30f};
    float lr[4] = {0.f,0.f,0.f,0.f};

    const unsigned short* kwb = kbh + (size_t)bh * NPAD * HD + (size_t)l15 * HD + lg*8;
    const unsigned short* vwb = Vt  + (size_t)bh * HD * NPAD + (size_t)l15 * NPAD + lg*8;

    for (int c = 0; c < 19; ++c) {
        const int n0 = c * 32;
        const unsigned short* kp = kwb + (size_t)n0 * HD;
        short8v bk00 = *(const short8v*)(kp);
        short8v bk01 = *(const short8v*)(kp + 32);
        short8v bk10 = *(const short8v*)(kp + 16*HD);
        short8v bk11 = *(const short8v*)(kp + 16*HD + 32);
        f32x4 s0 = {0.f,0.f,0.f,0.f}, s1 = {0.f,0.f,0.f,0.f};
        s0 = __builtin_amdgcn_mfma_f32_16x16x32_bf16(aq0, bk00, s0, 0, 0, 0);
        s0 = __builtin_amdgcn_mfma_f32_16x16x32_bf16(aq1, bk01, s0, 0, 0, 0);
        s1 = __builtin_amdgcn_mfma_f32_16x16x32_bf16(aq0, bk10, s1, 0, 0, 0);
        s1 = __builtin_amdgcn_mfma_f32_16x16x32_bf16(aq1, bk11, s1, 0, 0, 0);

        const int nc0 = n0 + l15;
        float p0[4], p1[4], al[4];
        #pragma unroll
        for (int r = 0; r < 4; ++r) {
            float a0 = (nc0      <= 576) ? s0[r] * 0.125f : -1e30f;
            float a1 = (nc0 + 16 <= 576) ? s1[r] * 0.125f : -1e30f;
            float tm = fmaxf(a0, a1);
            tm = fmaxf(tm, __shfl_xor(tm, 1, 64));
            tm = fmaxf(tm, __shfl_xor(tm, 2, 64));
            tm = fmaxf(tm, __shfl_xor(tm, 4, 64));
            tm = fmaxf(tm, __shfl_xor(tm, 8, 64));
            const float mn = fmaxf(mr[r], tm);
            al[r] = __expf(mr[r] - mn);
            mr[r] = mn;
            p0[r] = __expf(a0 - mn);
            p1[r] = __expf(a1 - mn);
            float ps = p0[r] + p1[r];
            ps += __shfl_xor(ps, 1, 64);
            ps += __shfl_xor(ps, 2, 64);
            ps += __shfl_xor(ps, 4, 64);
            ps += __shfl_xor(ps, 8, 64);
            lr[r] = lr[r] * al[r] + ps;
        }
        #pragma unroll
        for (int r = 0; r < 4; ++r) {
            O0[r] *= al[r]; O1[r] *= al[r]; O2[r] *= al[r]; O3[r] *= al[r];
        }
        #pragma unroll
        for (int r = 0; r < 4; ++r) {
            plds[w][lg*4 + r][l15]      = f2bf(p0[r]);
            plds[w][lg*4 + r][16 + l15] = f2bf(p1[r]);
        }
        asm volatile("s_waitcnt lgkmcnt(0)" ::: "memory");
        short8v pa = *(const short8v*)&plds[w][l15][lg*8];
        const unsigned short* vp = vwb + n0;
        short8v v0 = *(const short8v*)(vp);
        short8v v1 = *(const short8v*)(vp + 16*NPAD);
        short8v v2 = *(const short8v*)(vp + 32*NPAD);
        short8v v3 = *(const short8v*)(vp + 48*NPAD);
        O0 = __builtin_amdgcn_mfma_f32_16x16x32_bf16(pa, v0, O0, 0, 0, 0);
        O1 = __builtin_amdgcn_mfma_f32_16x16x32_bf16(pa, v1, O1, 0, 0, 0);
        O2 = __builtin_amdgcn_mfma_f32_16x16x32_bf16(pa, v2, O2, 0, 0, 0);
        O3 = __builtin_amdgcn_mfma_f32_16x16x32_bf16(pa, v3, O3, 0, 0, 0);
    }

    #pragma unroll
    for (int r = 0; r < 4; ++r) {
        const float inv = 1.f / lr[r];
        const int row = qt*64 + w*16 + lg*4 + r;
        if (row <= 576) {
            unsigned short* op = aobh + ((size_t)b * NN + row) * CC + h*HD + l15;
            op[0]  = f2bf(O0[r] * inv);
            op[16] = f2bf(O1[r] * inv);
            op[32] = f2bf(O2[r] * inv);
            op[48] = f2bf(O3[r] * inv);
        }
    }
}

// ---------------------------------------------------------------------------
// CLS path — bit-identical math to the passing R3/R4 draw
// ---------------------------------------------------------------------------
__global__ __launch_bounds__(256) void cls_scores(const float* __restrict__ qcls,
                                                  const float* __restrict__ kb,
                                                  float* __restrict__ P)
{
    const int bh = blockIdx.x;
    const int t = threadIdx.x;
    __shared__ float q[64];
    __shared__ float red[256];
    __shared__ float L[NN];
    if (t < 64) q[t] = qcls[(size_t)bh * 64 + t];
    __syncthreads();
    float lmax = -1e30f;
    for (int n = t; n < NN; n += 256) {
        const float* kr = kb + ((size_t)bh * NN + n) * HD;
        float acc = 0.f;
        #pragma unroll
        for (int d = 0; d < 64; ++d) acc = fmaf(q[d], kr[d], acc);
        const float l = acc * 0.125f;
        L[n] = l;
        lmax = fmaxf(lmax, l);
    }
    red[t] = lmax; __syncthreads();
    for (int s = 128; s > 0; s >>= 1) { if (t < s) red[t] = fmaxf(red[t], red[t+s]); __syncthreads(); }
    const float m = red[0]; __syncthreads();
    float z = 0.f;
    for (int n = t; n < NN; n += 256) { const float e = expf(L[n] - m); L[n] = e; z += e; }
    red[t] = z; __syncthreads();
    for (int s = 128; s > 0; s >>= 1) { if (t < s) red[t] += red[t+s]; __syncthreads(); }
    const float Z = red[0];
    for (int n = t; n < NN; n += 256) P[(size_t)bh * NN + n] = L[n] / Z;
}

__global__ __launch_bounds__(256) void cls_mean32(const float* __restrict__ P,
                                                  float* __restrict__ cls32,
                                                  float* __restrict__ out_cls)
{
    const int b = blockIdx.x;
    for (int j = threadIdx.x; j < NN - 1; j += 256) {
        float s = 0.f;
        #pragma unroll
        for (int h = 0; h < HH; ++h) s += P[((size_t)(b * HH + h)) * NN + 1 + j];
        const float v = s / 12.0f;
        cls32[b * 576 + j] = v;
        out_cls[b * 576 + j] = v;
    }
}

__global__ __launch_bounds__(256) void topk_rank(const float* __restrict__ cls32,
                                                 float* __restrict__ out_idx,
                                                 int* __restrict__ idxi)
{
    const int b = blockIdx.x;
    const int t = threadIdx.x;
    __shared__ float sv[576];
    for (int i = t; i < 576; i += 256) sv[i] = cls32[b * 576 + i];
    __syncthreads();
    for (int i = t; i < 576; i += 256) {
        const float vi = sv[i];
        int rank = 0;
        for (int j = 0; j < 576; ++j) {
            const float vj = sv[j];
            if (vj > vi || (vj == vi && j < i)) ++rank;
        }
        if (rank < LEFT) {
            out_idx[(size_t)b * LEFT + rank] = (float)i;
            idxi[(size_t)b * LEFT + rank] = i;
        }
    }
}

__global__ void write_index(const int* __restrict__ idxi, float* __restrict__ out_index)
{
    const int g4 = blockIdx.x * 256 + threadIdx.x;   // float4 index, 1,241,088 total
    const float v = (float)idxi[g4 / 192];           // 192 float4 per token row
    float4 o; o.x = v; o.y = v; o.z = v; o.w = v;
    ((float4*)out_index)[g4] = o;
}

// ---------------------------------------------------------------------------
extern "C" void kernel_launch(void* const* d_in, const int* in_sizes, int n_in,
                              void* d_out, int out_size, void* d_ws, size_t ws_size,
                              hipStream_t stream)
{
    const float* x      = (const float*)d_in[0];
    const float* qkv_w  = (const float*)d_in[1];
    const float* proj_w = (const float*)d_in[2];
    const float* proj_b = (const float*)d_in[3];
    float* out = (float*)d_out;

    // ws layout (bytes); total ~107.2 MB, within region proven in R1
    char* base = (char*)d_ws;
    float*          kb    = (float*)(base + 0);                   // [192][577][64] f32
    unsigned short* xbh   = (unsigned short*)(base +  28360704);  // [9344][768] bf16
    unsigned short* qbh   = (unsigned short*)(base +  42713088);  // [192][608][64] bf16
    unsigned short* kbh   = (unsigned short*)(base +  57655296);  // [192][608][64] bf16
    unsigned short* Vt    = (unsigned short*)(base +  72597504);  // [192][64][608] bf16
    unsigned short* aobh  = (unsigned short*)(base +  87539712);  // [9344][768] bf16
    unsigned short* wqkv  = (unsigned short*)(base + 101892096);  // [2304][768] bf16
    unsigned short* wpb   = (unsigned short*)(base + 105431040);  // [768][768] bf16
    float*          qcls  = (float*)(base + 106610688);           // [16][768] f32
    float*          P     = (float*)(base + 106659840);           // [192][577] f32
    float*          cls32 = (float*)(base + 107102976);           // [16][576] f32
    int*            idxi  = (int*)  (base + 107139840);           // [16][404] i32

    float* out_main  = out;                 // 7,090,176
    float* out_idx   = out + 7090176;       // 6,464
    float* out_index = out + 7096640;       // 4,964,352
    float* out_cls   = out + 12060992;      // 9,216

    convert3<<<9228, 256, 0, stream>>>(x, qkv_w, proj_w, xbh, wqkv, wpb);
    qcls_kernel<<<dim3(16, 3), 256, 0, stream>>>(x, qkv_w, qcls);
    k_gemm_fp32<<<dim3(73, 6), 256, 0, stream>>>(x, qkv_w, kb, kbh);
    qv_mfma<<<dim3(73, 12), 256, 0, stream>>>(xbh, wqkv, qbh, Vt);
    attn_mfma<<<BB * HH * NQT, 256, 0, stream>>>(qbh, kbh, Vt, aobh);
    proj_mfma<<<dim3(73, 6), 256, 0, stream>>>(aobh, wpb, proj_b, out_main);

    cls_scores<<<BB * HH, 256, 0, stream>>>(qcls, kb, P);
    cls_mean32<<<BB, 256, 0, stream>>>(P, cls32, out_cls);
    topk_rank<<<BB, 256, 0, stream>>>(cls32, out_idx, idxi);
    write_index<<<4848, 256, 0, stream>>>(idxi, out_index);
}